// Round 3
// baseline (551.174 us; speedup 1.0000x reference)
//
#include <hip/hip_runtime.h>

// ScaledDotProductAttention: b=16, n=2048, d=64, causal, temp=8.
// Outputs concatenated in d_out: out [b,n,d] fp32, attn [b,n,n] fp32.
//
// Round 3: barrier-free MFMA kernel.
//  - sdpa_convert: q,k -> bf16 copies; v -> bf16 TRANSPOSED Vt[b][d][n] (in d_ws).
//  - sdpa_main: block = (batch, 64 q-rows), 256 thr, NO __syncthreads.
//    All MFMA fragments are direct 16B global loads from the bf16 copies
//    (L2-resident: K+V = 768 KB/batch). Pass A: rowsums of exp(S).
//    Pass B: recompute S, normalize, write attn, PV via per-wave LDS
//    round-trip for the C->A layout transform (no cross-wave sharing).

constexpr int B = 16;
constexpr int N = 2048;
constexpr int D = 64;
constexpr float INV_TEMP = 0.125f; // 1/8
constexpr size_t QK_ELEMS = (size_t)B * N * D; // 2,097,152

typedef __attribute__((ext_vector_type(8))) short bf16x8; // 8 bf16 = 4 VGPRs
typedef __attribute__((ext_vector_type(4))) float f32x4;

__device__ __forceinline__ short f2bf(float f) {
    __bf16 h = (__bf16)f;
    return __builtin_bit_cast(short, h);
}

__global__ __launch_bounds__(256) void sdpa_convert(
    const float* __restrict__ q, const float* __restrict__ k, const float* __restrict__ v,
    short* __restrict__ qbf, short* __restrict__ kbf, short* __restrict__ vt)
{
    const int blk = blockIdx.x;
    const int t = threadIdx.x;
    if (blk < 512) {
        // V transpose: one 64x64 tile -> Vt[b][d][n]
        __shared__ short sT[64][72];
        const int b = blk >> 5, n0 = (blk & 31) * 64;
        const int srow = t >> 2, sd = (t & 3) * 16;
        const float4* src = (const float4*)(v + ((size_t)b * N + n0 + srow) * D + sd);
        float4 f0 = src[0], f1 = src[1], f2 = src[2], f3 = src[3];
        float vals[16] = {f0.x,f0.y,f0.z,f0.w, f1.x,f1.y,f1.z,f1.w,
                          f2.x,f2.y,f2.z,f2.w, f3.x,f3.y,f3.z,f3.w};
        short* dst = &sT[srow][sd];
#pragma unroll
        for (int i = 0; i < 16; ++i) dst[i] = f2bf(vals[i]);
        __syncthreads();
        const int d = t >> 2, nc = (t & 3) * 16;
        bf16x8 o0, o1;
#pragma unroll
        for (int i = 0; i < 8; ++i) o0[i] = sT[nc + i][d];
#pragma unroll
        for (int i = 0; i < 8; ++i) o1[i] = sT[nc + 8 + i][d];
        short* dstv = vt + ((size_t)b * D + d) * N + n0 + nc;
        *(bf16x8*)dstv = o0;
        *(bf16x8*)(dstv + 8) = o1;
    } else {
        // linear convert of q then k (8 elems/thread)
        size_t gi = (size_t)(blk - 512) * 2048 + (size_t)t * 8;
        const float* src; short* dst;
        if (gi < QK_ELEMS) { src = q + gi;             dst = qbf + gi; }
        else               { src = k + (gi - QK_ELEMS); dst = kbf + (gi - QK_ELEMS); }
        float4 f0 = ((const float4*)src)[0];
        float4 f1 = ((const float4*)src)[1];
        bf16x8 o;
        o[0]=f2bf(f0.x); o[1]=f2bf(f0.y); o[2]=f2bf(f0.z); o[3]=f2bf(f0.w);
        o[4]=f2bf(f1.x); o[5]=f2bf(f1.y); o[6]=f2bf(f1.z); o[7]=f2bf(f1.w);
        *(bf16x8*)dst = o;
    }
}

__global__ __launch_bounds__(256) void sdpa_main(
    const short* __restrict__ qbf, const short* __restrict__ kbf, const short* __restrict__ vt,
    float* __restrict__ out, float* __restrict__ attn)
{
    const int x = blockIdx.x;
    const int b = x >> 5;
    const int u = x & 31;
    // heavy/light pairing: qt = 0,31,1,30,...
    const int qt = (u & 1) ? (31 - (u >> 1)) : (u >> 1);
    const int qs = qt * 64;

    const int t    = threadIdx.x;
    const int w    = t >> 6;
    const int lane = t & 63;
    const int l15  = lane & 15;
    const int quad = lane >> 4;
    const int q8   = quad * 8;

    __shared__ __align__(16) short sP[4][16][72]; // per-wave P slice (no barrier needed)

    const short* kb  = kbf + (size_t)b * N * D;
    const short* vtb = vt  + (size_t)b * D * N;
    float* attn_b = attn + (size_t)b * N * N;

    // zero-fill masked (upper-triangle) cols of attn for this q-tile
    {
        const int srow = t >> 2;
        const int ce = (qt + 1) * 64;
        float4 z = {0.f, 0.f, 0.f, 0.f};
        float* arow = attn_b + (size_t)(qs + srow) * N;
        for (int c = ce + (t & 3) * 16; c < N; c += 64) {
            float4* p4 = (float4*)(arow + c);
            p4[0] = z; p4[1] = z; p4[2] = z; p4[3] = z;
        }
    }

    // Q A-fragments: loop-invariant, direct from global bf16
    const short* qrow = qbf + ((size_t)b * N + qs + w * 16 + l15) * D;
    const bf16x8 qa0 = *(const bf16x8*)(qrow + q8);
    const bf16x8 qa1 = *(const bf16x8*)(qrow + 32 + q8);

    // ---- pass A: row sums of exp(S) ----
    float rs[4] = {0.f, 0.f, 0.f, 0.f};
    for (int kt = 0; kt <= qt; ++kt) {
        const bool diag = (kt == qt);
#pragma unroll
        for (int nt = 0; nt < 4; ++nt) {
            const short* krow = kb + (size_t)(kt * 64 + nt * 16 + l15) * D;
            bf16x8 b0 = *(const bf16x8*)(krow + q8);
            bf16x8 b1 = *(const bf16x8*)(krow + 32 + q8);
            f32x4 c = {0.f, 0.f, 0.f, 0.f};
            c = __builtin_amdgcn_mfma_f32_16x16x32_bf16(qa0, b0, c, 0, 0, 0);
            c = __builtin_amdgcn_mfma_f32_16x16x32_bf16(qa1, b1, c, 0, 0, 0);
            const int col = nt * 16 + l15;
#pragma unroll
            for (int r = 0; r < 4; ++r) {
                const int rowl = w * 16 + quad * 4 + r;
                rs[r] += (!diag || col <= rowl) ? __expf(c[r] * INV_TEMP) : 0.f;
            }
        }
    }
    float inv[4];
#pragma unroll
    for (int r = 0; r < 4; ++r) {
        float s = rs[r];
        s += __shfl_xor(s, 1);
        s += __shfl_xor(s, 2);
        s += __shfl_xor(s, 4);
        s += __shfl_xor(s, 8);
        inv[r] = 1.f / s;
    }

    // ---- pass B: recompute, normalize, write attn, O += P.V ----
    f32x4 o[4];
#pragma unroll
    for (int nt = 0; nt < 4; ++nt) o[nt] = (f32x4){0.f, 0.f, 0.f, 0.f};

    for (int kt = 0; kt <= qt; ++kt) {
        const bool diag = (kt == qt);
#pragma unroll
        for (int nt = 0; nt < 4; ++nt) {
            const short* krow = kb + (size_t)(kt * 64 + nt * 16 + l15) * D;
            bf16x8 b0 = *(const bf16x8*)(krow + q8);
            bf16x8 b1 = *(const bf16x8*)(krow + 32 + q8);
            f32x4 c = {0.f, 0.f, 0.f, 0.f};
            c = __builtin_amdgcn_mfma_f32_16x16x32_bf16(qa0, b0, c, 0, 0, 0);
            c = __builtin_amdgcn_mfma_f32_16x16x32_bf16(qa1, b1, c, 0, 0, 0);
            const int col = nt * 16 + l15;
            float* arow = attn_b + (size_t)(qs + w * 16 + quad * 4) * N + kt * 64 + col;
#pragma unroll
            for (int r = 0; r < 4; ++r) {
                const int rowl = w * 16 + quad * 4 + r;
                float p = (!diag || col <= rowl) ? __expf(c[r] * INV_TEMP) * inv[r] : 0.f;
                arow[(size_t)r * N] = p;
                sP[w][quad * 4 + r][col] = f2bf(p);
            }
        }
        // PV: A-frags from own wave's sP slice, B-frags direct from Vt (global)
#pragma unroll
        for (int kc = 0; kc < 2; ++kc) {
            bf16x8 a = *(const bf16x8*)&sP[w][l15][kc * 32 + q8];
#pragma unroll
            for (int nt = 0; nt < 4; ++nt) {
                const short* vrow = vtb + (size_t)(nt * 16 + l15) * N + kt * 64 + kc * 32 + q8;
                bf16x8 vf = *(const bf16x8*)vrow;
                o[nt] = __builtin_amdgcn_mfma_f32_16x16x32_bf16(a, vf, o[nt], 0, 0, 0);
            }
        }
    }

    // ---- epilogue: write O (already normalized) ----
#pragma unroll
    for (int nt = 0; nt < 4; ++nt) {
        float* orow = out + ((size_t)(b * N + qs + w * 16 + quad * 4)) * D + nt * 16 + l15;
#pragma unroll
        for (int r = 0; r < 4; ++r) orow[(size_t)r * D] = o[nt][r];
    }
}

extern "C" void kernel_launch(void* const* d_in, const int* in_sizes, int n_in,
                              void* d_out, int out_size, void* d_ws, size_t ws_size,
                              hipStream_t stream) {
    const float* q = (const float*)d_in[0];
    const float* k = (const float*)d_in[1];
    const float* v = (const float*)d_in[2];
    // d_in[3] (mask) is static causal — not read.

    float* out  = (float*)d_out;
    float* attn = out + (size_t)B * N * D;

    short* qbf = (short*)d_ws;          // 4 MB
    short* kbf = qbf + QK_ELEMS;        // 4 MB
    short* vtb = kbf + QK_ELEMS;        // 4 MB (transposed)

    sdpa_convert<<<dim3(2560), dim3(256), 0, stream>>>(q, k, v, qbf, kbf, vtb);
    sdpa_main<<<dim3(B * 32), dim3(256), 0, stream>>>(qbf, kbf, vtb, out, attn);
}